// Round 1
// baseline (4089.560 us; speedup 1.0000x reference)
//
#include <hip/hip_runtime.h>
#include <math.h>

#define EE 819200          // edges total
#define BGRAPH 8192        // graphs
constexpr int TPB = 512;   // threads per block, fused GCN kernel

// ---------------------------------------------------------------------------
// Fused per-graph 3-layer GCN + global max pool.
// Block b handles graph b: nodes [b*50, b*50+50), edges [b*100, b*100+100).
// All intermediates live in LDS. Input buffers padded to stride FIN+1 to
// break LDS bank conflicts on the k-strided reads in the tile GEMM.
// ---------------------------------------------------------------------------

template<int FIN, int FOUT>
__device__ inline void tile_gemm(const float* __restrict__ Xin,   // [52][FIN+1] LDS
                                 const float* __restrict__ W,     // [FIN][FOUT] global
                                 float* __restrict__ H)           // [52][FOUT] LDS
{
    constexpr int LDI = FIN + 1;
    constexpr int FT  = (FOUT + 3) / 4;
    constexpr int NT  = 13 * FT;          // 13 node tiles (52 rows) x feature tiles
    for (int t = threadIdx.x; t < NT; t += TPB) {
        const int tn = t % 13;
        const int tf = t / 13;
        const int n0 = tn * 4, f0 = tf * 4;
        // clamped offsets for the (only) partial feature tile
        const int o1 = (f0 + 1 < FOUT) ? 1 : 0;
        const int o2 = (f0 + 2 < FOUT) ? 2 : 0;
        const int o3 = (f0 + 3 < FOUT) ? 3 : 0;
        float acc[4][4] = {};
        const float* Xr = Xin + n0 * LDI;
        for (int k = 0; k < FIN; ++k) {
            const float x0 = Xr[k];
            const float x1 = Xr[LDI + k];
            const float x2 = Xr[2 * LDI + k];
            const float x3 = Xr[3 * LDI + k];
            const float* wp = W + k * FOUT + f0;
            const float w0 = wp[0];
            const float w1 = wp[o1];
            const float w2 = wp[o2];
            const float w3 = wp[o3];
            acc[0][0] += x0 * w0; acc[0][1] += x0 * w1; acc[0][2] += x0 * w2; acc[0][3] += x0 * w3;
            acc[1][0] += x1 * w0; acc[1][1] += x1 * w1; acc[1][2] += x1 * w2; acc[1][3] += x1 * w3;
            acc[2][0] += x2 * w0; acc[2][1] += x2 * w1; acc[2][2] += x2 * w2; acc[2][3] += x2 * w3;
            acc[3][0] += x3 * w0; acc[3][1] += x3 * w1; acc[3][2] += x3 * w2; acc[3][3] += x3 * w3;
        }
#pragma unroll
        for (int i = 0; i < 4; ++i) {
            const int n = n0 + i;
#pragma unroll
            for (int j = 0; j < 4; ++j) {
                const int f = f0 + j;
                if (f < FOUT) H[n * FOUT + f] = acc[i][j];
            }
        }
    }
}

// out = relu(bias + selfw*h + sum_{in-edges} norm*h[src]); layers 1/2 write LDS
// buffer (stride FOUT+1, pad rows zeroed); layer 3 feeds the max-pool instead.
template<int FOUT, bool DOMAX>
__device__ inline void aggregate(const float* __restrict__ H,      // [52][FOUT]
                                 const float* __restrict__ bias,   // [FOUT] global
                                 const int*   __restrict__ insrc,
                                 const float* __restrict__ insn,
                                 const int*   __restrict__ inoff,
                                 const float* __restrict__ selfw,
                                 float* __restrict__ out,          // [52][FOUT+1] or null
                                 unsigned* __restrict__ gmax)      // [FOUT] or null
{
    constexpr int LDO = FOUT + 1;
    for (int idx = threadIdx.x; idx < 50 * FOUT; idx += TPB) {
        const int n = idx / FOUT;
        const int f = idx - n * FOUT;
        float acc = bias[f] + selfw[n] * H[n * FOUT + f];
        const int j1 = inoff[n + 1];
        for (int j = inoff[n]; j < j1; ++j)
            acc += insn[j] * H[insrc[j] * FOUT + f];
        acc = fmaxf(acc, 0.0f);
        if (DOMAX) atomicMax(&gmax[f], __float_as_uint(acc));
        else       out[n * LDO + f] = acc;
    }
    if (!DOMAX) {
        for (int idx = threadIdx.x; idx < 2 * LDO; idx += TPB)
            out[50 * LDO + idx] = 0.0f;   // zero pad rows 50,51
    }
}

__global__ __launch_bounds__(TPB, 1) void gcn_fused(
    const float* __restrict__ X,        // [N,78]
    const int*   __restrict__ srcA,     // [E]
    const int*   __restrict__ dstA,     // [E]
    const float* __restrict__ Wc1, const float* __restrict__ bc1,
    const float* __restrict__ Wc2, const float* __restrict__ bc2,
    const float* __restrict__ Wc3, const float* __restrict__ bc3,
    float* __restrict__ G)              // [B,312]
{
    __shared__ float sA[52 * 157];      // input buf (X0 @stride79, x2 @stride157)
    __shared__ float sB[52 * 79];       // x1 buf
    __shared__ float sH[52 * 312];      // h buf
    __shared__ int   es[100], ed[100];
    __shared__ int   insrc[100];
    __shared__ float insn[100];
    __shared__ int   inoff[51];
    __shared__ int   cnt[50];
    __shared__ float dinvs[52];
    __shared__ float selfw[52];
    __shared__ unsigned gmax[312];

    const int b   = blockIdx.x;
    const int nb  = b * 50;
    const int eb  = b * 100;
    const int tid = threadIdx.x;

    for (int i = tid; i < 50; i += TPB) cnt[i] = 0;
    for (int e = tid; e < 100; e += TPB) {
        es[e] = srcA[eb + e] - nb;
        ed[e] = dstA[eb + e] - nb;
    }
    __syncthreads();
    for (int e = tid; e < 100; e += TPB) atomicAdd(&cnt[ed[e]], 1);
    __syncthreads();
    for (int n = tid; n < 52; n += TPB) {
        float dv = 0.0f;
        if (n < 50) dv = 1.0f / sqrtf((float)cnt[n] + 1.0f);
        dinvs[n] = dv;
        selfw[n] = dv * dv;
    }
    __syncthreads();
    if (tid == 0) {                      // tiny serial prefix sum (50 entries)
        int off = 0;
        for (int n = 0; n < 50; ++n) { inoff[n] = off; off += cnt[n]; }
        inoff[50] = off;
    }
    __syncthreads();
    for (int n = tid; n < 50; n += TPB) cnt[n] = 0;
    __syncthreads();
    for (int e = tid; e < 100; e += TPB) {   // counting-sort edges by dst
        const int d = ed[e];
        const int p = inoff[d] + atomicAdd(&cnt[d], 1);
        insrc[p] = es[e];
        insn[p]  = dinvs[es[e]] * dinvs[d];
    }
    // load X tile [50,78] -> sA stride 79, zero pad rows
    for (int idx = tid; idx < 50 * 78; idx += TPB) {
        const int n = idx / 78, c = idx - n * 78;
        sA[n * 79 + c] = X[(size_t)(nb + n) * 78 + c];
    }
    for (int idx = tid; idx < 2 * 79; idx += TPB) sA[50 * 79 + idx] = 0.0f;
    __syncthreads();

    // layer 1: 78 -> 78
    tile_gemm<78, 78>(sA, Wc1, sH);
    __syncthreads();
    aggregate<78, false>(sH, bc1, insrc, insn, inoff, selfw, sB, nullptr);
    __syncthreads();

    // layer 2: 78 -> 156
    tile_gemm<78, 156>(sB, Wc2, sH);
    __syncthreads();
    aggregate<156, false>(sH, bc2, insrc, insn, inoff, selfw, sA, nullptr);
    __syncthreads();

    // layer 3: 156 -> 312, fused max pool
    for (int f = tid; f < 312; f += TPB) gmax[f] = 0u;
    tile_gemm<156, 312>(sA, Wc3, sH);
    __syncthreads();
    aggregate<312, true>(sH, bc3, insrc, insn, inoff, selfw, nullptr, gmax);
    __syncthreads();
    for (int f = tid; f < 312; f += TPB)
        G[(size_t)b * 312 + f] = __uint_as_float(gmax[f]);
}

// ---------------------------------------------------------------------------
// Generic fp32 tiled GEMM: C[m, coff+n] = act(A[M,K] @ W[K,N] + bias[N])
// BM=BN=64, BK=16, 256 threads, 4x4 micro-tile. ldc/coff support writing into
// a strided concat buffer.
// ---------------------------------------------------------------------------
template<bool RELU>
__global__ __launch_bounds__(256) void gemm_f32(
    const float* __restrict__ A, const float* __restrict__ W,
    const float* __restrict__ bias, float* __restrict__ C,
    int M, int N, int K, int ldc, int coff)
{
    __shared__ float As[64][17];   // padded: conflict-free k-reads
    __shared__ float Ws[16][64];
    const int bm = blockIdx.x * 64;
    const int bn = blockIdx.y * 64;
    const int tid = threadIdx.x;
    const int tx = tid & 15;       // n dim
    const int ty = tid >> 4;       // m dim
    float acc[4][4] = {};

    for (int k0 = 0; k0 < K; k0 += 16) {
        for (int i = tid; i < 64 * 16; i += 256) {
            const int m = i >> 4, kk = i & 15;
            const int gm = bm + m, gk = k0 + kk;
            As[m][kk] = (gm < M && gk < K) ? A[(size_t)gm * K + gk] : 0.0f;
        }
        for (int i = tid; i < 16 * 64; i += 256) {
            const int kk = i >> 6, n = i & 63;
            const int gk = k0 + kk, gn = bn + n;
            Ws[kk][n] = (gk < K && gn < N) ? W[(size_t)gk * N + gn] : 0.0f;
        }
        __syncthreads();
#pragma unroll
        for (int kk = 0; kk < 16; ++kk) {
            const float4 wv = *reinterpret_cast<const float4*>(&Ws[kk][tx * 4]);
            float a[4];
#pragma unroll
            for (int i = 0; i < 4; ++i) a[i] = As[ty * 4 + i][kk];
#pragma unroll
            for (int i = 0; i < 4; ++i) {
                acc[i][0] += a[i] * wv.x;
                acc[i][1] += a[i] * wv.y;
                acc[i][2] += a[i] * wv.z;
                acc[i][3] += a[i] * wv.w;
            }
        }
        __syncthreads();
    }
#pragma unroll
    for (int i = 0; i < 4; ++i) {
        const int gm = bm + ty * 4 + i;
        if (gm >= M) continue;
#pragma unroll
        for (int j = 0; j < 4; ++j) {
            const int gn = bn + tx * 4 + j;
            if (gn >= N) continue;
            float v = acc[i][j] + bias[gn];
            if (RELU) v = fmaxf(v, 0.0f);
            C[(size_t)gm * ldc + coff + gn] = v;
        }
    }
}

// ---------------------------------------------------------------------------
// Row-wise L2 normalize: Y[r,:] = X[r,:] / max(||X[r,:]||_2, 1e-12), 954 cols
// ---------------------------------------------------------------------------
__global__ __launch_bounds__(256) void l2norm_rows(
    const float* __restrict__ X, float* __restrict__ Y)
{
    const int r = blockIdx.x;
    const float* row = X + (size_t)r * 954;
    float ss = 0.0f;
    for (int c = threadIdx.x; c < 954; c += 256) { const float v = row[c]; ss += v * v; }
    for (int off = 32; off > 0; off >>= 1) ss += __shfl_down(ss, off, 64);
    __shared__ float part[4];
    if ((threadIdx.x & 63) == 0) part[threadIdx.x >> 6] = ss;
    __syncthreads();
    if (threadIdx.x == 0) {
        const float s = part[0] + part[1] + part[2] + part[3];
        part[0] = 1.0f / fmaxf(sqrtf(s), 1e-12f);
    }
    __syncthreads();
    const float sc = part[0];
    for (int c = threadIdx.x; c < 954; c += 256)
        Y[(size_t)r * 954 + c] = row[c] * sc;
}

// ---------------------------------------------------------------------------

extern "C" void kernel_launch(void* const* d_in, const int* in_sizes, int n_in,
                              void* d_out, int out_size, void* d_ws, size_t ws_size,
                              hipStream_t stream)
{
    (void)in_sizes; (void)n_in; (void)out_size; (void)ws_size;
    const float* x1   = (const float*)d_in[0];
    const int*   ei1  = (const int*)d_in[1];
    const float* x2   = (const float*)d_in[3];
    const int*   ei2  = (const int*)d_in[4];
    const float* cell = (const float*)d_in[6];
    const float* Wc1 = (const float*)d_in[7],  *bc1 = (const float*)d_in[8];
    const float* Wc2 = (const float*)d_in[9],  *bc2 = (const float*)d_in[10];
    const float* Wc3 = (const float*)d_in[11], *bc3 = (const float*)d_in[12];
    const float* Wg1 = (const float*)d_in[13], *bg1 = (const float*)d_in[14];
    const float* Wg2 = (const float*)d_in[15], *bg2 = (const float*)d_in[16];
    const float* Wr1 = (const float*)d_in[17], *br1 = (const float*)d_in[18];
    const float* Wr2 = (const float*)d_in[19], *br2 = (const float*)d_in[20];
    const float* Wr3 = (const float*)d_in[21], *br3 = (const float*)d_in[22];
    const float* Wf1 = (const float*)d_in[23], *bf1 = (const float*)d_in[24];
    const float* Wf2 = (const float*)d_in[25], *bf2 = (const float*)d_in[26];
    const float* Wo  = (const float*)d_in[27], *bo  = (const float*)d_in[28];
    float* out = (float*)d_out;
    float* ws  = (float*)d_ws;

    // workspace layout (floats): ~107 MB total
    size_t o = 0;
    float* G1  = ws + o; o += (size_t)BGRAPH * 312;
    float* G2  = ws + o; o += (size_t)BGRAPH * 312;
    float* T   = ws + o; o += (size_t)BGRAPH * 156;
    float* CVN = ws + o; o += (size_t)BGRAPH * 954;
    float* C1  = ws + o; o += (size_t)BGRAPH * 512;
    float* C2  = ws + o; o += (size_t)BGRAPH * 256;
    float* XC  = ws + o; o += (size_t)BGRAPH * 384;
    float* Hh1 = ws + o; o += (size_t)BGRAPH * 256;
    float* Hh2 = ws + o; o += (size_t)BGRAPH * 128;

    // drug branches (GCN x3 + maxpool), fused per graph
    gcn_fused<<<BGRAPH, TPB, 0, stream>>>(x1, ei1, ei1 + EE, Wc1, bc1, Wc2, bc2, Wc3, bc3, G1);
    gcn_fused<<<BGRAPH, TPB, 0, stream>>>(x2, ei2, ei2 + EE, Wc1, bc1, Wc2, bc2, Wc3, bc3, G2);

    // cell row normalize
    l2norm_rows<<<BGRAPH, 256, 0, stream>>>(cell, CVN);

    dim3 blk(256);
    auto gg = [](int M, int N) { return dim3((unsigned)((M + 63) / 64), (unsigned)((N + 63) / 64)); };

    // drug heads -> XC[:,0:128] and XC[:,128:256]
    gemm_f32<true ><<<gg(8192, 156), blk, 0, stream>>>(G1, Wg1, bg1, T,  8192, 156, 312, 156, 0);
    gemm_f32<false><<<gg(8192, 128), blk, 0, stream>>>(T,  Wg2, bg2, XC, 8192, 128, 156, 384, 0);
    gemm_f32<true ><<<gg(8192, 156), blk, 0, stream>>>(G2, Wg1, bg1, T,  8192, 156, 312, 156, 0);
    gemm_f32<false><<<gg(8192, 128), blk, 0, stream>>>(T,  Wg2, bg2, XC, 8192, 128, 156, 384, 128);

    // cell MLP -> XC[:,256:384]
    gemm_f32<true ><<<gg(8192, 512), blk, 0, stream>>>(CVN, Wr1, br1, C1, 8192, 512, 954, 512, 0);
    gemm_f32<true ><<<gg(8192, 256), blk, 0, stream>>>(C1,  Wr2, br2, C2, 8192, 256, 512, 256, 0);
    gemm_f32<false><<<gg(8192, 128), blk, 0, stream>>>(C2,  Wr3, br3, XC, 8192, 128, 256, 384, 256);

    // head
    gemm_f32<true ><<<gg(8192, 256), blk, 0, stream>>>(XC,  Wf1, bf1, Hh1, 8192, 256, 384, 256, 0);
    gemm_f32<true ><<<gg(8192, 128), blk, 0, stream>>>(Hh1, Wf2, bf2, Hh2, 8192, 128, 256, 128, 0);
    gemm_f32<false><<<gg(8192, 2),   blk, 0, stream>>>(Hh2, Wo,  bo,  out, 8192, 2,   128, 2,   0);
}

// Round 2
// 2967.179 us; speedup vs baseline: 1.3783x; 1.3783x over previous
//
#include <hip/hip_runtime.h>
#include <math.h>

#define EE 819200          // edges total
#define BGRAPH 8192        // graphs
constexpr int TPB = 512;   // threads per block, fused GCN kernel
constexpr int LDX = 157;   // LDS row stride (odd: kills bank conflicts)

// ---------------------------------------------------------------------------
// Fused per-graph 3-layer GCN + global max pool, using the algebraic identity
//   GCNConv(X) = Â(XW)+b = (ÂX)W + b
// so we aggregate FIRST (on the smaller input dim), then GEMM. Layer 3's GEMM
// fuses bias+relu+maxpool in its epilogue -> no 312-wide buffer needed.
// Two ping-pong LDS buffers [52][157]; pad rows 50,51 kept zero.
// ---------------------------------------------------------------------------

template<int FIN>
__device__ inline void agg_block(const float* __restrict__ in,
                                 float* __restrict__ out,
                                 const int*   __restrict__ insrc,
                                 const float* __restrict__ insn,
                                 const int*   __restrict__ inoff,
                                 const float* __restrict__ selfw)
{
    for (int idx = threadIdx.x; idx < 50 * FIN; idx += TPB) {
        const int n = idx / FIN;
        const int f = idx - n * FIN;
        float acc = selfw[n] * in[n * LDX + f];
        const int j1 = inoff[n + 1];
        for (int j = inoff[n]; j < j1; ++j)
            acc += insn[j] * in[insrc[j] * LDX + f];
        out[n * LDX + f] = acc;
    }
}

// GEMM: Y = relu(Xa @ W + b)   (Xa: [52][LDX] LDS, W: [FIN][FOUT] global)
// Micro-tile: 4 nodes x FTW features. Feature-major lane mapping: a wave's
// lanes share the A-row reads (LDS broadcast, free) and load W coalesced.
// FTW per layer chosen so 13*(FOUT/FTW) == 507 (all threads active).
// POOL: fold bias+relu+max-over-nodes into epilogue via LDS atomicMax.
template<int FIN, int FOUT, int FTW, bool POOL>
__device__ inline void gemm_block(const float* __restrict__ Xa,
                                  const float* __restrict__ W,
                                  const float* __restrict__ bias,
                                  float* __restrict__ Yout,
                                  unsigned* __restrict__ gmax)
{
    constexpr int NFT = FOUT / FTW;       // 39
    const int t = threadIdx.x;
    if (t >= 13 * NFT) return;
    const int tf = t % NFT;
    const int tn = t / NFT;
    const int f0 = tf * FTW, n0 = tn * 4;
    float acc[4][FTW];
#pragma unroll
    for (int i = 0; i < 4; ++i)
#pragma unroll
        for (int j = 0; j < FTW; ++j) acc[i][j] = 0.0f;

    const float* Xr = Xa + n0 * LDX;
#pragma unroll 2
    for (int k = 0; k < FIN; ++k) {
        const float a0 = Xr[k];
        const float a1 = Xr[LDX + k];
        const float a2 = Xr[2 * LDX + k];
        const float a3 = Xr[3 * LDX + k];
        const float* wp = W + (size_t)k * FOUT + f0;
        float wv[FTW];
        if constexpr (FTW == 8) {
            *(float4*)&wv[0] = *(const float4*)wp;
            *(float4*)&wv[4] = *(const float4*)(wp + 4);
        } else if constexpr (FTW == 4) {
            *(float4*)&wv[0] = *(const float4*)wp;
        } else {
            *(float2*)&wv[0] = *(const float2*)wp;
        }
#pragma unroll
        for (int j = 0; j < FTW; ++j) {
            acc[0][j] += a0 * wv[j];
            acc[1][j] += a1 * wv[j];
            acc[2][j] += a2 * wv[j];
            acc[3][j] += a3 * wv[j];
        }
    }

    if constexpr (POOL) {
#pragma unroll
        for (int j = 0; j < FTW; ++j) {
            float m = 0.0f;   // relu floor doubles as pool identity
            const float bj = bias[f0 + j];
#pragma unroll
            for (int i = 0; i < 4; ++i)
                if (n0 + i < 50) m = fmaxf(m, acc[i][j] + bj);
            atomicMax(&gmax[f0 + j], __float_as_uint(m));
        }
    } else {
#pragma unroll
        for (int i = 0; i < 4; ++i) {
            if (n0 + i < 50) {
#pragma unroll
                for (int j = 0; j < FTW; ++j)
                    Yout[(n0 + i) * LDX + f0 + j] =
                        fmaxf(acc[i][j] + bias[f0 + j], 0.0f);
            }
        }
    }
}

__global__ __launch_bounds__(TPB, 4) void gcn_fused(
    const float* __restrict__ X,        // [N,78]
    const int*   __restrict__ srcA,     // [E]
    const int*   __restrict__ dstA,     // [E]
    const float* __restrict__ Wc1, const float* __restrict__ bc1,
    const float* __restrict__ Wc2, const float* __restrict__ bc2,
    const float* __restrict__ Wc3, const float* __restrict__ bc3,
    float* __restrict__ G)              // [B,312]
{
    __shared__ float bufA[52 * LDX];
    __shared__ float bufB[52 * LDX];
    __shared__ int   es[100], ed[100];
    __shared__ int   insrc[100];
    __shared__ float insn[100];
    __shared__ int   inoff[51];
    __shared__ int   cnt[50];
    __shared__ float dinvs[50];
    __shared__ float selfw[50];
    __shared__ unsigned gmax[312];

    const int b   = blockIdx.x;
    const int nb  = b * 50;
    const int eb  = b * 100;
    const int tid = threadIdx.x;

    for (int i = tid; i < 50; i += TPB) cnt[i] = 0;
    for (int e = tid; e < 100; e += TPB) {
        es[e] = srcA[eb + e] - nb;
        ed[e] = dstA[eb + e] - nb;
    }
    for (int i = tid; i < 2 * LDX; i += TPB) {   // keep pad rows zero
        bufA[50 * LDX + i] = 0.0f;
        bufB[50 * LDX + i] = 0.0f;
    }
    for (int f = tid; f < 312; f += TPB) gmax[f] = 0u;
    __syncthreads();
    for (int e = tid; e < 100; e += TPB) atomicAdd(&cnt[ed[e]], 1);
    __syncthreads();
    for (int n = tid; n < 50; n += TPB) {
        const float dv = 1.0f / sqrtf((float)cnt[n] + 1.0f);
        dinvs[n] = dv;
        selfw[n] = dv * dv;
    }
    __syncthreads();
    if (tid == 0) {                      // tiny serial prefix sum (50 entries)
        int off = 0;
        for (int n = 0; n < 50; ++n) { inoff[n] = off; off += cnt[n]; }
        inoff[50] = off;
    }
    __syncthreads();
    for (int n = tid; n < 50; n += TPB) cnt[n] = 0;
    __syncthreads();
    for (int e = tid; e < 100; e += TPB) {   // counting-sort edges by dst
        const int d = ed[e];
        const int p = inoff[d] + atomicAdd(&cnt[d], 1);
        insrc[p] = es[e];
        insn[p]  = dinvs[es[e]] * dinvs[d];
    }
    // load X tile [50,78] -> bufA
    for (int idx = tid; idx < 50 * 78; idx += TPB) {
        const int n = idx / 78, c = idx - n * 78;
        bufA[n * LDX + c] = X[(size_t)(nb + n) * 78 + c];
    }
    __syncthreads();

    // layer 1: agg(78) then 78->78 GEMM
    agg_block<78>(bufA, bufB, insrc, insn, inoff, selfw);
    __syncthreads();
    gemm_block<78, 78, 2, false>(bufB, Wc1, bc1, bufA, nullptr);
    __syncthreads();

    // layer 2: agg(78) then 78->156 GEMM
    agg_block<78>(bufA, bufB, insrc, insn, inoff, selfw);
    __syncthreads();
    gemm_block<78, 156, 4, false>(bufB, Wc2, bc2, bufA, nullptr);
    __syncthreads();

    // layer 3: agg(156) then 156->312 GEMM + fused bias/relu/maxpool
    agg_block<156>(bufA, bufB, insrc, insn, inoff, selfw);
    __syncthreads();
    gemm_block<156, 312, 8, true>(bufB, Wc3, bc3, nullptr, gmax);
    __syncthreads();
    for (int f = tid; f < 312; f += TPB)
        G[(size_t)b * 312 + f] = __uint_as_float(gmax[f]);
}

// ---------------------------------------------------------------------------
// Generic fp32 tiled GEMM: C[m, coff+n] = act(A[M,K] @ W[K,N] + bias[N])
// BM=BN=64, BK=16, 256 threads, 4x4 micro-tile. ldc/coff support writing into
// a strided concat buffer.
// ---------------------------------------------------------------------------
template<bool RELU>
__global__ __launch_bounds__(256) void gemm_f32(
    const float* __restrict__ A, const float* __restrict__ W,
    const float* __restrict__ bias, float* __restrict__ C,
    int M, int N, int K, int ldc, int coff)
{
    __shared__ float As[64][17];   // padded: conflict-free k-reads
    __shared__ float Ws[16][64];
    const int bm = blockIdx.x * 64;
    const int bn = blockIdx.y * 64;
    const int tid = threadIdx.x;
    const int tx = tid & 15;       // n dim
    const int ty = tid >> 4;       // m dim
    float acc[4][4] = {};

    for (int k0 = 0; k0 < K; k0 += 16) {
        for (int i = tid; i < 64 * 16; i += 256) {
            const int m = i >> 4, kk = i & 15;
            const int gm = bm + m, gk = k0 + kk;
            As[m][kk] = (gm < M && gk < K) ? A[(size_t)gm * K + gk] : 0.0f;
        }
        for (int i = tid; i < 16 * 64; i += 256) {
            const int kk = i >> 6, n = i & 63;
            const int gk = k0 + kk, gn = bn + n;
            Ws[kk][n] = (gk < K && gn < N) ? W[(size_t)gk * N + gn] : 0.0f;
        }
        __syncthreads();
#pragma unroll
        for (int kk = 0; kk < 16; ++kk) {
            const float4 wv = *reinterpret_cast<const float4*>(&Ws[kk][tx * 4]);
            float a[4];
#pragma unroll
            for (int i = 0; i < 4; ++i) a[i] = As[ty * 4 + i][kk];
#pragma unroll
            for (int i = 0; i < 4; ++i) {
                acc[i][0] += a[i] * wv.x;
                acc[i][1] += a[i] * wv.y;
                acc[i][2] += a[i] * wv.z;
                acc[i][3] += a[i] * wv.w;
            }
        }
        __syncthreads();
    }
#pragma unroll
    for (int i = 0; i < 4; ++i) {
        const int gm = bm + ty * 4 + i;
        if (gm >= M) continue;
#pragma unroll
        for (int j = 0; j < 4; ++j) {
            const int gn = bn + tx * 4 + j;
            if (gn >= N) continue;
            float v = acc[i][j] + bias[gn];
            if (RELU) v = fmaxf(v, 0.0f);
            C[(size_t)gm * ldc + coff + gn] = v;
        }
    }
}

// ---------------------------------------------------------------------------
// Row-wise L2 normalize: Y[r,:] = X[r,:] / max(||X[r,:]||_2, 1e-12), 954 cols
// ---------------------------------------------------------------------------
__global__ __launch_bounds__(256) void l2norm_rows(
    const float* __restrict__ X, float* __restrict__ Y)
{
    const int r = blockIdx.x;
    const float* row = X + (size_t)r * 954;
    float ss = 0.0f;
    for (int c = threadIdx.x; c < 954; c += 256) { const float v = row[c]; ss += v * v; }
    for (int off = 32; off > 0; off >>= 1) ss += __shfl_down(ss, off, 64);
    __shared__ float part[4];
    if ((threadIdx.x & 63) == 0) part[threadIdx.x >> 6] = ss;
    __syncthreads();
    if (threadIdx.x == 0) {
        const float s = part[0] + part[1] + part[2] + part[3];
        part[0] = 1.0f / fmaxf(sqrtf(s), 1e-12f);
    }
    __syncthreads();
    const float sc = part[0];
    for (int c = threadIdx.x; c < 954; c += 256)
        Y[(size_t)r * 954 + c] = row[c] * sc;
}

// ---------------------------------------------------------------------------

extern "C" void kernel_launch(void* const* d_in, const int* in_sizes, int n_in,
                              void* d_out, int out_size, void* d_ws, size_t ws_size,
                              hipStream_t stream)
{
    (void)in_sizes; (void)n_in; (void)out_size; (void)ws_size;
    const float* x1   = (const float*)d_in[0];
    const int*   ei1  = (const int*)d_in[1];
    const float* x2   = (const float*)d_in[3];
    const int*   ei2  = (const int*)d_in[4];
    const float* cell = (const float*)d_in[6];
    const float* Wc1 = (const float*)d_in[7],  *bc1 = (const float*)d_in[8];
    const float* Wc2 = (const float*)d_in[9],  *bc2 = (const float*)d_in[10];
    const float* Wc3 = (const float*)d_in[11], *bc3 = (const float*)d_in[12];
    const float* Wg1 = (const float*)d_in[13], *bg1 = (const float*)d_in[14];
    const float* Wg2 = (const float*)d_in[15], *bg2 = (const float*)d_in[16];
    const float* Wr1 = (const float*)d_in[17], *br1 = (const float*)d_in[18];
    const float* Wr2 = (const float*)d_in[19], *br2 = (const float*)d_in[20];
    const float* Wr3 = (const float*)d_in[21], *br3 = (const float*)d_in[22];
    const float* Wf1 = (const float*)d_in[23], *bf1 = (const float*)d_in[24];
    const float* Wf2 = (const float*)d_in[25], *bf2 = (const float*)d_in[26];
    const float* Wo  = (const float*)d_in[27], *bo  = (const float*)d_in[28];
    float* out = (float*)d_out;
    float* ws  = (float*)d_ws;

    // workspace layout (floats)
    size_t o = 0;
    float* G1  = ws + o; o += (size_t)BGRAPH * 312;
    float* G2  = ws + o; o += (size_t)BGRAPH * 312;
    float* T   = ws + o; o += (size_t)BGRAPH * 156;
    float* CVN = ws + o; o += (size_t)BGRAPH * 954;
    float* C1  = ws + o; o += (size_t)BGRAPH * 512;
    float* C2  = ws + o; o += (size_t)BGRAPH * 256;
    float* XC  = ws + o; o += (size_t)BGRAPH * 384;
    float* Hh1 = ws + o; o += (size_t)BGRAPH * 256;
    float* Hh2 = ws + o; o += (size_t)BGRAPH * 128;

    // drug branches (GCN x3 + maxpool), fused per graph
    gcn_fused<<<BGRAPH, TPB, 0, stream>>>(x1, ei1, ei1 + EE, Wc1, bc1, Wc2, bc2, Wc3, bc3, G1);
    gcn_fused<<<BGRAPH, TPB, 0, stream>>>(x2, ei2, ei2 + EE, Wc1, bc1, Wc2, bc2, Wc3, bc3, G2);

    // cell row normalize
    l2norm_rows<<<BGRAPH, 256, 0, stream>>>(cell, CVN);

    dim3 blk(256);
    auto gg = [](int M, int N) { return dim3((unsigned)((M + 63) / 64), (unsigned)((N + 63) / 64)); };

    // drug heads -> XC[:,0:128] and XC[:,128:256]
    gemm_f32<true ><<<gg(8192, 156), blk, 0, stream>>>(G1, Wg1, bg1, T,  8192, 156, 312, 156, 0);
    gemm_f32<false><<<gg(8192, 128), blk, 0, stream>>>(T,  Wg2, bg2, XC, 8192, 128, 156, 384, 0);
    gemm_f32<true ><<<gg(8192, 156), blk, 0, stream>>>(G2, Wg1, bg1, T,  8192, 156, 312, 156, 0);
    gemm_f32<false><<<gg(8192, 128), blk, 0, stream>>>(T,  Wg2, bg2, XC, 8192, 128, 156, 384, 128);

    // cell MLP -> XC[:,256:384]
    gemm_f32<true ><<<gg(8192, 512), blk, 0, stream>>>(CVN, Wr1, br1, C1, 8192, 512, 954, 512, 0);
    gemm_f32<true ><<<gg(8192, 256), blk, 0, stream>>>(C1,  Wr2, br2, C2, 8192, 256, 512, 256, 0);
    gemm_f32<false><<<gg(8192, 128), blk, 0, stream>>>(C2,  Wr3, br3, XC, 8192, 128, 256, 384, 256);

    // head
    gemm_f32<true ><<<gg(8192, 256), blk, 0, stream>>>(XC,  Wf1, bf1, Hh1, 8192, 256, 384, 256, 0);
    gemm_f32<true ><<<gg(8192, 128), blk, 0, stream>>>(Hh1, Wf2, bf2, Hh2, 8192, 128, 256, 128, 0);
    gemm_f32<false><<<gg(8192, 2),   blk, 0, stream>>>(Hh2, Wo,  bo,  out, 8192, 2,   128, 2,   0);
}